// Round 3
// baseline (398.859 us; speedup 1.0000x reference)
//
#include <hip/hip_runtime.h>
#include <math.h>

// Problem constants (match reference)
constexpr int NB   = 8;            // batch
constexpr int ND   = 8;            // embedding dim
constexpr int NH   = 512;
constexpr int NW   = 1024;
constexpr int NP   = NH * NW;      // pixels per image = 524288
constexpr int NG   = NP / 4;       // float4 groups per image = 131072
constexpr int NK   = 5;            // instance labels 1..NK

constexpr int BPB1 = 256;          // pass1 blocks per image (2048 total)
constexpr int GPB1 = NG / BPB1;    // 512 float4 groups per block
constexpr int IT1  = GPB1 / 32;    // 16 iterations (32 groups per iter)
constexpr int BPB2 = 256;          // pass2 blocks per image (2048 total)
constexpr int GPB2 = NG / BPB2;    // 512 groups per block, 2 iters of 256

constexpr float DELTA_V     = 0.5f;
constexpr float TWO_DELTA_D = 6.0f;   // 2 * DELTA_D
constexpr float GAMMA       = 0.001f;

__device__ __forceinline__ float rfl(float x) {
    return __int_as_float(__builtin_amdgcn_readfirstlane(__float_as_int(x)));
}

__device__ __forceinline__ float wave_sum(float v) {
#pragma unroll
    for (int off = 32; off > 0; off >>= 1) v += __shfl_down(v, off, 64);
    return v;
}

// ---------------- Pass 1: per-(b,k) embedding sums + counts ----------------
// Dim-split layout: wave w handles dims {2w, 2w+1}; each 32-lane half-wave owns
// one embedding plane. Per-thread state ~30 VGPR -> 8 waves/SIMD occupancy.
// Counts accumulated by dim-0 half-wave only.
__global__ __launch_bounds__(256, 8) void pass1_kernel(const float* __restrict__ emb,
                                                       const int* __restrict__ mask,
                                                       float* __restrict__ sums,   // [NB][NK][ND]
                                                       float* __restrict__ cnts) { // [NB][NK]
    const int b    = blockIdx.x / BPB1;
    const int blk  = blockIdx.x % BPB1;
    const int wave = threadIdx.x >> 6;
    const int lane = threadIdx.x & 63;
    const int gl   = lane & 31;
    const int d    = wave * 2 + (lane >> 5);
    const bool dzero = (d == 0);

    const float4* __restrict__ ep = (const float4*)emb + (long)(b * ND + d) * NG;
    const int4*   __restrict__ mp = (const int4*)mask + (long)b * NG;

    float a0 = 0.f, a1 = 0.f, a2 = 0.f, a3 = 0.f, a4 = 0.f;
    float n0 = 0.f, n1 = 0.f, n2 = 0.f, n3 = 0.f, n4 = 0.f;

    const int base = blk * GPB1 + gl;
#pragma unroll 4
    for (int it = 0; it < IT1; ++it) {
        const int g = base + it * 32;
        const int4   m = mp[g];
        const float4 e = ep[g];
#define PIX(LAB, EJ) { const int lab = (LAB); const float ej = (EJ); \
        a0 += (lab == 1) ? ej : 0.f; a1 += (lab == 2) ? ej : 0.f; \
        a2 += (lab == 3) ? ej : 0.f; a3 += (lab == 4) ? ej : 0.f; \
        a4 += (lab == 5) ? ej : 0.f; \
        if (dzero) { n0 += (lab == 1) ? 1.f : 0.f; n1 += (lab == 2) ? 1.f : 0.f; \
                     n2 += (lab == 3) ? 1.f : 0.f; n3 += (lab == 4) ? 1.f : 0.f; \
                     n4 += (lab == 5) ? 1.f : 0.f; } }
        PIX(m.x, e.x) PIX(m.y, e.y) PIX(m.z, e.z) PIX(m.w, e.w)
#undef PIX
    }

    // reduce within each 32-lane half (each half owns one dim -> final for block)
#pragma unroll
    for (int off = 16; off > 0; off >>= 1) {
        a0 += __shfl_down(a0, off, 32); a1 += __shfl_down(a1, off, 32);
        a2 += __shfl_down(a2, off, 32); a3 += __shfl_down(a3, off, 32);
        a4 += __shfl_down(a4, off, 32);
    }
    if (wave == 0) {
#pragma unroll
        for (int off = 16; off > 0; off >>= 1) {
            n0 += __shfl_down(n0, off, 32); n1 += __shfl_down(n1, off, 32);
            n2 += __shfl_down(n2, off, 32); n3 += __shfl_down(n3, off, 32);
            n4 += __shfl_down(n4, off, 32);
        }
    }

    __shared__ float pl[ND][NK];
    __shared__ float pc[NK];
    if (gl == 0) {
        pl[d][0] = a0; pl[d][1] = a1; pl[d][2] = a2; pl[d][3] = a3; pl[d][4] = a4;
    }
    if (threadIdx.x == 0) { pc[0] = n0; pc[1] = n1; pc[2] = n2; pc[3] = n3; pc[4] = n4; }
    __syncthreads();
    const int t = threadIdx.x;
    if (t < NK * ND)                       // t = k*8 + d
        atomicAdd(&sums[b * NK * ND + t], pl[t & 7][t >> 3]);
    else if (t < NK * ND + NK)
        atomicAdd(&cnts[b * NK + (t - NK * ND)], pc[t - NK * ND]);
}

// ---------------- Pass 2: variance hinge sums + fused last-block epilogue ----------------
__global__ __launch_bounds__(256, 6) void pass2_kernel(const float* __restrict__ emb,
                                                       const int* __restrict__ mask,
                                                       const float* __restrict__ sums,
                                                       const float* __restrict__ cnts,
                                                       float* __restrict__ vsums,  // [NB][NK]
                                                       int* __restrict__ ticket,
                                                       float* __restrict__ out) {
    const int b   = blockIdx.x / BPB2;
    const int blk = blockIdx.x % BPB2;
    const int base = blk * GPB2;

    // centers in SGPRs (wave-uniform; readfirstlane forces scalar regs)
    const float* sp = sums + b * NK * ND;
    const float i0 = rfl(1.f / fmaxf(cnts[b * NK + 0], 1.f));
    const float i1 = rfl(1.f / fmaxf(cnts[b * NK + 1], 1.f));
    const float i2 = rfl(1.f / fmaxf(cnts[b * NK + 2], 1.f));
    const float i3 = rfl(1.f / fmaxf(cnts[b * NK + 3], 1.f));
    const float i4 = rfl(1.f / fmaxf(cnts[b * NK + 4], 1.f));
    const float4 c0l = make_float4(rfl(sp[0])*i0,  rfl(sp[1])*i0,  rfl(sp[2])*i0,  rfl(sp[3])*i0);
    const float4 c0h = make_float4(rfl(sp[4])*i0,  rfl(sp[5])*i0,  rfl(sp[6])*i0,  rfl(sp[7])*i0);
    const float4 c1l = make_float4(rfl(sp[8])*i1,  rfl(sp[9])*i1,  rfl(sp[10])*i1, rfl(sp[11])*i1);
    const float4 c1h = make_float4(rfl(sp[12])*i1, rfl(sp[13])*i1, rfl(sp[14])*i1, rfl(sp[15])*i1);
    const float4 c2l = make_float4(rfl(sp[16])*i2, rfl(sp[17])*i2, rfl(sp[18])*i2, rfl(sp[19])*i2);
    const float4 c2h = make_float4(rfl(sp[20])*i2, rfl(sp[21])*i2, rfl(sp[22])*i2, rfl(sp[23])*i2);
    const float4 c3l = make_float4(rfl(sp[24])*i3, rfl(sp[25])*i3, rfl(sp[26])*i3, rfl(sp[27])*i3);
    const float4 c3h = make_float4(rfl(sp[28])*i3, rfl(sp[29])*i3, rfl(sp[30])*i3, rfl(sp[31])*i3);
    const float4 c4l = make_float4(rfl(sp[32])*i4, rfl(sp[33])*i4, rfl(sp[34])*i4, rfl(sp[35])*i4);
    const float4 c4h = make_float4(rfl(sp[36])*i4, rfl(sp[37])*i4, rfl(sp[38])*i4, rfl(sp[39])*i4);

    const float4* __restrict__ emb4 = (const float4*)emb + (long)b * ND * NG;
    const int4*   __restrict__ m4p  = (const int4*)mask + (long)b * NG;

    float v0 = 0.f, v1 = 0.f, v2 = 0.f, v3 = 0.f, v4 = 0.f;

    for (int it = threadIdx.x; it < GPB2; it += 256) {
        const int g = base + it;
        const int4   m  = m4p[g];
        const float4 e0 = emb4[g];
        const float4 e1 = emb4[g + NG];
        const float4 e2 = emb4[g + 2 * NG];
        const float4 e3 = emb4[g + 3 * NG];
        const float4 e4 = emb4[g + 4 * NG];
        const float4 e5 = emb4[g + 5 * NG];
        const float4 e6 = emb4[g + 6 * NG];
        const float4 e7 = emb4[g + 7 * NG];

#define SEL2(F) ((lab == 1) ? c0##F : (lab == 2) ? c1##F : (lab == 3) ? c2##F : \
                 (lab == 4) ? c3##F : c4##F)
#define PIX2(LAB, CM) { const int lab = (LAB); \
        float dd = e0.CM - SEL2(l.x); float dsq = dd * dd; \
        dd = e1.CM - SEL2(l.y); dsq = fmaf(dd, dd, dsq); \
        dd = e2.CM - SEL2(l.z); dsq = fmaf(dd, dd, dsq); \
        dd = e3.CM - SEL2(l.w); dsq = fmaf(dd, dd, dsq); \
        dd = e4.CM - SEL2(h.x); dsq = fmaf(dd, dd, dsq); \
        dd = e5.CM - SEL2(h.y); dsq = fmaf(dd, dd, dsq); \
        dd = e6.CM - SEL2(h.z); dsq = fmaf(dd, dd, dsq); \
        dd = e7.CM - SEL2(h.w); dsq = fmaf(dd, dd, dsq); \
        const float dist = sqrtf(dsq); \
        const float hv = fmaxf(dist - DELTA_V, 0.f); \
        const float val = hv * hv; \
        v0 += (lab == 1) ? val : 0.f; v1 += (lab == 2) ? val : 0.f; \
        v2 += (lab == 3) ? val : 0.f; v3 += (lab == 4) ? val : 0.f; \
        v4 += (lab == 5) ? val : 0.f; }

        PIX2(m.x, x) PIX2(m.y, y) PIX2(m.z, z) PIX2(m.w, w)
#undef PIX2
#undef SEL2
    }

    __shared__ float part[4][NK];
    const int lane = threadIdx.x & 63;
    const int wave = threadIdx.x >> 6;
#define RED2(V, IDX) { const float r = wave_sum(V); if (lane == 0) part[wave][IDX] = r; }
    RED2(v0, 0) RED2(v1, 1) RED2(v2, 2) RED2(v3, 3) RED2(v4, 4)
#undef RED2
    __syncthreads();
    if (threadIdx.x < NK) {
        const float s = part[0][threadIdx.x] + part[1][threadIdx.x] +
                        part[2][threadIdx.x] + part[3][threadIdx.x];
        atomicAdd(&vsums[b * NK + threadIdx.x], s);
    }
    __syncthreads();   // drain this block's vsums atomics before ticketing

    // ---- last-block-done epilogue (CUB-style ticket) ----
    __shared__ int lastflag;
    if (threadIdx.x == 0) {
        __threadfence();
        lastflag = (atomicAdd(ticket, 1) == NB * BPB2 - 1) ? 1 : 0;
    }
    __syncthreads();
    if (!lastflag) return;
    __threadfence();

    __shared__ float bl[4][NB];
    const int bb = threadIdx.x;
    if (bb < NB) {
        float cc[NK];
        bool  pres[NK];
        float c[NK][ND];
        float N = 0.f;
#pragma unroll
        for (int k = 0; k < NK; ++k) {
            cc[k]   = cnts[bb * NK + k];            // stable since pass1
            pres[k] = cc[k] > 0.f;
            if (pres[k]) N += 1.f;
            const float inv = 1.f / fmaxf(cc[k], 1.f);
#pragma unroll
            for (int dd2 = 0; dd2 < ND; ++dd2)
                c[k][dd2] = sums[bb * NK * ND + k * ND + dd2] * inv;
        }
        // variance loss (vsums read at coherence point via atomic RMW +0)
        float lv = 0.f;
#pragma unroll
        for (int k = 0; k < NK; ++k) {
            const float vs = atomicAdd(&vsums[bb * NK + k], 0.f);
            if (pres[k]) lv += vs / fmaxf(cc[k], 1.f);
        }
        lv /= fmaxf(N, 1.f);
        // distance loss
        float ld = 0.f;
#pragma unroll
        for (int i = 0; i < NK; ++i)
#pragma unroll
            for (int j = i + 1; j < NK; ++j)
                if (pres[i] && pres[j]) {
                    float dsq = 0.f;
#pragma unroll
                    for (int dd2 = 0; dd2 < ND; ++dd2) {
                        const float df = c[i][dd2] - c[j][dd2];
                        dsq = fmaf(df, df, dsq);
                    }
                    const float tt = fmaxf(TWO_DELTA_D - sqrtf(dsq), 0.f);
                    ld += tt * tt;
                }
        const float npairs = N * (N - 1.f) * 0.5f;
        ld /= (N > 1.f) ? npairs : 1.f;
        // regularization
        float lr = 0.f;
#pragma unroll
        for (int k = 0; k < NK; ++k)
            if (pres[k]) {
                float sq = 0.f;
#pragma unroll
                for (int dd2 = 0; dd2 < ND; ++dd2) sq = fmaf(c[k][dd2], c[k][dd2], sq);
                lr += sqrtf(sq);
            }
        lr /= fmaxf(N, 1.f);

        const float has = (N > 0.f) ? 1.f : 0.f;
        bl[0][bb] = lv * has;
        bl[1][bb] = ld * has;
        bl[2][bb] = lr * has;
        bl[3][bb] = has;
    }
    __syncthreads();
    if (threadIdx.x == 0) {
        float tv = 0.f, td = 0.f, tr = 0.f, hs = 0.f;
        for (int i = 0; i < NB; ++i) {
            tv += bl[0][i]; td += bl[1][i]; tr += bl[2][i]; hs += bl[3][i];
        }
        const float denom = fmaxf(hs, 1.f);
        tv /= denom; td /= denom; tr /= denom;
        out[0] = tv + td + GAMMA * tr;
        out[1] = tv;
        out[2] = td;
        out[3] = tr;
    }
}

extern "C" void kernel_launch(void* const* d_in, const int* in_sizes, int n_in,
                              void* d_out, int out_size, void* d_ws, size_t ws_size,
                              hipStream_t stream) {
    const float* emb  = (const float*)d_in[0];
    const int*   mask = (const int*)d_in[1];
    float* out = (float*)d_out;

    float* sums   = (float*)d_ws;                 // NB*NK*ND = 320 floats
    float* cnts   = sums + NB * NK * ND;          // NB*NK    = 40
    float* vsums  = cnts + NB * NK;               // NB*NK    = 40
    int*   ticket = (int*)(vsums + NB * NK);      // 1 int

    hipMemsetAsync(d_ws, 0,
                   (size_t)(NB * NK * ND + 2 * NB * NK) * sizeof(float) + sizeof(int),
                   stream);

    pass1_kernel<<<dim3(NB * BPB1), dim3(256), 0, stream>>>(emb, mask, sums, cnts);
    pass2_kernel<<<dim3(NB * BPB2), dim3(256), 0, stream>>>(emb, mask, sums, cnts,
                                                            vsums, ticket, out);
}

// Round 4
// 257.440 us; speedup vs baseline: 1.5493x; 1.5493x over previous
//
#include <hip/hip_runtime.h>
#include <math.h>

// Problem constants (match reference)
constexpr int NB   = 8;            // batch
constexpr int ND   = 8;            // embedding dim
constexpr int NH   = 512;
constexpr int NW   = 1024;
constexpr int NP   = NH * NW;      // pixels per image = 524288
constexpr int NG   = NP / 4;       // float4 groups per image = 131072
constexpr int NK   = 5;            // instance labels 1..NK

constexpr int BPB1 = 256;          // pass1 blocks per image (2048 total)
constexpr int GPB1 = NG / BPB1;    // 512 float4 groups per block
constexpr int IT1  = GPB1 / 32;    // 16 iterations (32 groups per iter per half-wave)
constexpr int BPB2 = 256;          // pass2 blocks per image (2048 total)
constexpr int GPB2 = NG / BPB2;    // 512 groups per block

constexpr float DELTA_V     = 0.5f;
constexpr float TWO_DELTA_D = 6.0f;   // 2 * DELTA_D
constexpr float GAMMA       = 0.001f;

__device__ __forceinline__ float wave_sum(float v) {
#pragma unroll
    for (int off = 32; off > 0; off >>= 1) v += __shfl_down(v, off, 64);
    return v;
}

// ---------------- Pass 1: per-(b,k) embedding sums + counts ----------------
// Dim-split: wave w handles dims {2w, 2w+1}; each 32-lane half-wave owns one
// embedding plane. Hand-unrolled x2: >=4 independent loads in flight/thread.
// Plain launch_bounds (NO min-waves cap -> no spill; natural VGPR ~45 -> 8 w/SIMD).
__global__ __launch_bounds__(256) void pass1_kernel(const float* __restrict__ emb,
                                                    const int* __restrict__ mask,
                                                    float* __restrict__ sums,   // [NB][NK][ND]
                                                    float* __restrict__ cnts) { // [NB][NK]
    const int b    = blockIdx.x / BPB1;
    const int blk  = blockIdx.x % BPB1;
    const int wave = threadIdx.x >> 6;
    const int lane = threadIdx.x & 63;
    const int gl   = lane & 31;
    const int d    = wave * 2 + (lane >> 5);
    const bool dzero = (d == 0);

    const float4* __restrict__ ep = (const float4*)emb + (long)(b * ND + d) * NG;
    const int4*   __restrict__ mp = (const int4*)mask + (long)b * NG;

    float a0 = 0.f, a1 = 0.f, a2 = 0.f, a3 = 0.f, a4 = 0.f;
    float n0 = 0.f, n1 = 0.f, n2 = 0.f, n3 = 0.f, n4 = 0.f;

    const int base = blk * GPB1 + gl;

#define PIX1(LAB, EJ) { const int lab = (LAB); const float ej = (EJ); \
        a0 += (lab == 1) ? ej : 0.f; a1 += (lab == 2) ? ej : 0.f; \
        a2 += (lab == 3) ? ej : 0.f; a3 += (lab == 4) ? ej : 0.f; \
        a4 += (lab == 5) ? ej : 0.f; \
        if (dzero) { n0 += (lab == 1) ? 1.f : 0.f; n1 += (lab == 2) ? 1.f : 0.f; \
                     n2 += (lab == 3) ? 1.f : 0.f; n3 += (lab == 4) ? 1.f : 0.f; \
                     n4 += (lab == 5) ? 1.f : 0.f; } }

#pragma unroll
    for (int it = 0; it < IT1; it += 2) {
        const int ga = base + it * 32;
        const int gb = ga + 32;
        const int4   ma = mp[ga];
        const float4 ea = ep[ga];
        const int4   mb = mp[gb];
        const float4 eb = ep[gb];
        PIX1(ma.x, ea.x) PIX1(ma.y, ea.y) PIX1(ma.z, ea.z) PIX1(ma.w, ea.w)
        PIX1(mb.x, eb.x) PIX1(mb.y, eb.y) PIX1(mb.z, eb.z) PIX1(mb.w, eb.w)
    }
#undef PIX1

    // reduce within each 32-lane half (each half owns one dim -> final for block)
#pragma unroll
    for (int off = 16; off > 0; off >>= 1) {
        a0 += __shfl_down(a0, off, 32); a1 += __shfl_down(a1, off, 32);
        a2 += __shfl_down(a2, off, 32); a3 += __shfl_down(a3, off, 32);
        a4 += __shfl_down(a4, off, 32);
    }
    if (wave == 0) {
#pragma unroll
        for (int off = 16; off > 0; off >>= 1) {
            n0 += __shfl_down(n0, off, 32); n1 += __shfl_down(n1, off, 32);
            n2 += __shfl_down(n2, off, 32); n3 += __shfl_down(n3, off, 32);
            n4 += __shfl_down(n4, off, 32);
        }
    }

    __shared__ float pl[ND][NK];
    __shared__ float pc[NK];
    if (gl == 0) {
        pl[d][0] = a0; pl[d][1] = a1; pl[d][2] = a2; pl[d][3] = a3; pl[d][4] = a4;
    }
    if (threadIdx.x == 0) { pc[0] = n0; pc[1] = n1; pc[2] = n2; pc[3] = n3; pc[4] = n4; }
    __syncthreads();
    const int t = threadIdx.x;
    if (t < NK * ND)                       // t = k*8 + d
        atomicAdd(&sums[b * NK * ND + t], pl[t & 7][t >> 3]);
    else if (t < NK * ND + NK)
        atomicAdd(&cnts[b * NK + (t - NK * ND)], pc[t - NK * ND]);
}

// ---------------- Pass 2: per-(b,k) variance hinge sums (R2-proven form) ----------------
__global__ __launch_bounds__(256) void pass2_kernel(const float* __restrict__ emb,
                                                    const int* __restrict__ mask,
                                                    const float* __restrict__ sums,
                                                    const float* __restrict__ cnts,
                                                    float* __restrict__ vsums) { // [NB][NK]
    const int b   = blockIdx.x / BPB2;
    const int blk = blockIdx.x % BPB2;
    const long base = (long)blk * GPB2;

    // centers in named registers (wave-uniform loads -> compiler scalarizes)
    const float* sp = sums + b * NK * ND;
    const float i0 = 1.f / fmaxf(cnts[b * NK + 0], 1.f);
    const float i1 = 1.f / fmaxf(cnts[b * NK + 1], 1.f);
    const float i2 = 1.f / fmaxf(cnts[b * NK + 2], 1.f);
    const float i3 = 1.f / fmaxf(cnts[b * NK + 3], 1.f);
    const float i4 = 1.f / fmaxf(cnts[b * NK + 4], 1.f);
    const float4 c0l = make_float4(sp[0]*i0,  sp[1]*i0,  sp[2]*i0,  sp[3]*i0);
    const float4 c0h = make_float4(sp[4]*i0,  sp[5]*i0,  sp[6]*i0,  sp[7]*i0);
    const float4 c1l = make_float4(sp[8]*i1,  sp[9]*i1,  sp[10]*i1, sp[11]*i1);
    const float4 c1h = make_float4(sp[12]*i1, sp[13]*i1, sp[14]*i1, sp[15]*i1);
    const float4 c2l = make_float4(sp[16]*i2, sp[17]*i2, sp[18]*i2, sp[19]*i2);
    const float4 c2h = make_float4(sp[20]*i2, sp[21]*i2, sp[22]*i2, sp[23]*i2);
    const float4 c3l = make_float4(sp[24]*i3, sp[25]*i3, sp[26]*i3, sp[27]*i3);
    const float4 c3h = make_float4(sp[28]*i3, sp[29]*i3, sp[30]*i3, sp[31]*i3);
    const float4 c4l = make_float4(sp[32]*i4, sp[33]*i4, sp[34]*i4, sp[35]*i4);
    const float4 c4h = make_float4(sp[36]*i4, sp[37]*i4, sp[38]*i4, sp[39]*i4);

    const float4* __restrict__ emb4 = (const float4*)emb + (long)b * ND * NG;
    const int4*   __restrict__ m4p  = (const int4*)mask + (long)b * NG;

    float v0 = 0.f, v1 = 0.f, v2 = 0.f, v3 = 0.f, v4 = 0.f;

    for (int it = threadIdx.x; it < GPB2; it += 256) {
        const long g = base + it;
        const int4   m  = m4p[g];
        const float4 e0 = emb4[g];
        const float4 e1 = emb4[g + (long)NG];
        const float4 e2 = emb4[g + 2L * NG];
        const float4 e3 = emb4[g + 3L * NG];
        const float4 e4 = emb4[g + 4L * NG];
        const float4 e5 = emb4[g + 5L * NG];
        const float4 e6 = emb4[g + 6L * NG];
        const float4 e7 = emb4[g + 7L * NG];

#define SEL2(F) ((lab == 1) ? c0##F : (lab == 2) ? c1##F : (lab == 3) ? c2##F : \
                 (lab == 4) ? c3##F : c4##F)
#define PIX2(LAB, CM) { const int lab = (LAB); \
        float dd = e0.CM - SEL2(l.x); float dsq = dd * dd; \
        dd = e1.CM - SEL2(l.y); dsq = fmaf(dd, dd, dsq); \
        dd = e2.CM - SEL2(l.z); dsq = fmaf(dd, dd, dsq); \
        dd = e3.CM - SEL2(l.w); dsq = fmaf(dd, dd, dsq); \
        dd = e4.CM - SEL2(h.x); dsq = fmaf(dd, dd, dsq); \
        dd = e5.CM - SEL2(h.y); dsq = fmaf(dd, dd, dsq); \
        dd = e6.CM - SEL2(h.z); dsq = fmaf(dd, dd, dsq); \
        dd = e7.CM - SEL2(h.w); dsq = fmaf(dd, dd, dsq); \
        const float dist = sqrtf(dsq); \
        const float hv = fmaxf(dist - DELTA_V, 0.f); \
        const float val = hv * hv; \
        v0 += (lab == 1) ? val : 0.f; v1 += (lab == 2) ? val : 0.f; \
        v2 += (lab == 3) ? val : 0.f; v3 += (lab == 4) ? val : 0.f; \
        v4 += (lab == 5) ? val : 0.f; }

        PIX2(m.x, x) PIX2(m.y, y) PIX2(m.z, z) PIX2(m.w, w)
#undef PIX2
#undef SEL2
    }

    __shared__ float part[4][NK];
    const int lane = threadIdx.x & 63;
    const int wave = threadIdx.x >> 6;
#define RED2(V, IDX) { const float r = wave_sum(V); if (lane == 0) part[wave][IDX] = r; }
    RED2(v0, 0) RED2(v1, 1) RED2(v2, 2) RED2(v3, 3) RED2(v4, 4)
#undef RED2
    __syncthreads();
    if (threadIdx.x < NK) {
        const float s = part[0][threadIdx.x] + part[1][threadIdx.x] +
                        part[2][threadIdx.x] + part[3][threadIdx.x];
        atomicAdd(&vsums[b * NK + threadIdx.x], s);
    }
}

// ---------------- Final: tiny O(B*K^2) epilogue, 8-way parallel over batch ----------------
__global__ void final_kernel(const float* __restrict__ sums,
                             const float* __restrict__ cnts,
                             const float* __restrict__ vsums,
                             float* __restrict__ out) {
    __shared__ float bl[4][NB];
    const int bb = threadIdx.x;
    if (bb < NB) {
        float cc[NK];
        bool  pres[NK];
        float c[NK][ND];
        float N = 0.f;
#pragma unroll
        for (int k = 0; k < NK; ++k) {
            cc[k]   = cnts[bb * NK + k];
            pres[k] = cc[k] > 0.f;
            if (pres[k]) N += 1.f;
            const float inv = 1.f / fmaxf(cc[k], 1.f);
#pragma unroll
            for (int d = 0; d < ND; ++d)
                c[k][d] = sums[bb * NK * ND + k * ND + d] * inv;
        }
        // variance loss
        float lv = 0.f;
#pragma unroll
        for (int k = 0; k < NK; ++k)
            if (pres[k]) lv += vsums[bb * NK + k] / fmaxf(cc[k], 1.f);
        lv /= fmaxf(N, 1.f);
        // distance loss (pairwise i<j)
        float ld = 0.f;
#pragma unroll
        for (int i = 0; i < NK; ++i)
#pragma unroll
            for (int j = i + 1; j < NK; ++j)
                if (pres[i] && pres[j]) {
                    float dsq = 0.f;
#pragma unroll
                    for (int d = 0; d < ND; ++d) {
                        const float df = c[i][d] - c[j][d];
                        dsq = fmaf(df, df, dsq);
                    }
                    const float t = fmaxf(TWO_DELTA_D - sqrtf(dsq), 0.f);
                    ld += t * t;
                }
        const float npairs = N * (N - 1.f) * 0.5f;
        ld /= (N > 1.f) ? npairs : 1.f;
        // regularization
        float lr = 0.f;
#pragma unroll
        for (int k = 0; k < NK; ++k)
            if (pres[k]) {
                float sq = 0.f;
#pragma unroll
                for (int d = 0; d < ND; ++d) sq = fmaf(c[k][d], c[k][d], sq);
                lr += sqrtf(sq);
            }
        lr /= fmaxf(N, 1.f);

        const float has = (N > 0.f) ? 1.f : 0.f;
        bl[0][bb] = lv * has;
        bl[1][bb] = ld * has;
        bl[2][bb] = lr * has;
        bl[3][bb] = has;
    }
    __syncthreads();
    if (threadIdx.x == 0) {
        float tv = 0.f, td = 0.f, tr = 0.f, hs = 0.f;
        for (int i = 0; i < NB; ++i) {
            tv += bl[0][i]; td += bl[1][i]; tr += bl[2][i]; hs += bl[3][i];
        }
        const float denom = fmaxf(hs, 1.f);
        tv /= denom; td /= denom; tr /= denom;
        out[0] = tv + td + GAMMA * tr;
        out[1] = tv;
        out[2] = td;
        out[3] = tr;
    }
}

extern "C" void kernel_launch(void* const* d_in, const int* in_sizes, int n_in,
                              void* d_out, int out_size, void* d_ws, size_t ws_size,
                              hipStream_t stream) {
    const float* emb  = (const float*)d_in[0];
    const int*   mask = (const int*)d_in[1];
    float* out = (float*)d_out;

    float* sums  = (float*)d_ws;                 // NB*NK*ND = 320 floats
    float* cnts  = sums + NB * NK * ND;          // NB*NK    = 40
    float* vsums = cnts + NB * NK;               // NB*NK    = 40

    hipMemsetAsync(d_ws, 0, (size_t)(NB * NK * ND + 2 * NB * NK) * sizeof(float), stream);

    pass1_kernel<<<dim3(NB * BPB1), dim3(256), 0, stream>>>(emb, mask, sums, cnts);
    pass2_kernel<<<dim3(NB * BPB2), dim3(256), 0, stream>>>(emb, mask, sums, cnts, vsums);
    final_kernel<<<1, 64, 0, stream>>>(sums, cnts, vsums, out);
}